// Round 1
// baseline (582.435 us; speedup 1.0000x reference)
//
#include <hip/hip_runtime.h>

#define N_NODES 50000
#define N_EDGES 800000
#define HID 128

typedef _Float16 f16;
typedef _Float16 half8 __attribute__((ext_vector_type(8)));
typedef _Float16 half4 __attribute__((ext_vector_type(4)));
typedef float f32x4 __attribute__((ext_vector_type(4)));

// ---- workspace layout (bytes) ----
#define OFF_MI   0UL                 // 50000*128*4  = 25,600,000
#define OFF_H16  25600000UL          // 50000*128*2  = 12,800,000
#define OFF_BP1  38400000UL          // 9*4*128*8*2  = 73,728
#define OFF_BP2  38473728UL          // 4*4*128*8*2  = 32,768
#define OFF_BN1  38506496UL          // 8*4*128*8*2  = 65,536
#define OFF_BN2  38572032UL          // 32,768      -> total 38,604,800

#define XS 296   // X tile stride (f16 elems): 128 hdst | 128 hsrc | 24 attr | 8 zero | 8 unused
#define TS 136   // T tile stride
#define YS 264   // node Y tile stride (256 + pad)

// Pack W[K][128] f32 -> f16 B-fragment layout: Bp[((ks*4+q)*128+n)*8 + j] = W[k][n], k=(ks*4+q)*8+j
// We1 rows are permuted: X k-order is [hdst(0..127)->We1 row 24+k | hsrc(128..255)->row 24+k | attr(256..279)->row k-256 | pad=0]
__global__ __launch_bounds__(256) void pack_weights(
    const float* __restrict__ We1, const float* __restrict__ We2,
    const float* __restrict__ Wn1, const float* __restrict__ Wn2,
    f16* __restrict__ Bp1, f16* __restrict__ Bp2,
    f16* __restrict__ BN1, f16* __restrict__ BN2) {
  int i = blockIdx.x * 256 + threadIdx.x;   // 0..102399
  if (i < 36864) {                          // We1: 9 ksteps
    int j = i & 7, n = (i >> 3) & 127, qk = i >> 10;   // qk = ks*4+q
    int k = qk * 8 + j;
    float v = 0.f;
    if (k < 256) v = We1[(24 + k) * 128 + n];
    else if (k < 280) v = We1[(k - 256) * 128 + n];
    Bp1[i] = (f16)v;
  } else if (i < 53248) {                   // We2: 4 ksteps
    int l = i - 36864;
    int j = l & 7, n = (l >> 3) & 127, qk = l >> 10;
    Bp2[l] = (f16)We2[(qk * 8 + j) * 128 + n];
  } else if (i < 86016) {                   // Wn1: 8 ksteps
    int l = i - 53248;
    int j = l & 7, n = (l >> 3) & 127, qk = l >> 10;
    BN1[l] = (f16)Wn1[(qk * 8 + j) * 128 + n];
  } else if (i < 102400) {                  // Wn2: 4 ksteps
    int l = i - 86016;
    int j = l & 7, n = (l >> 3) & 127, qk = l >> 10;
    BN2[l] = (f16)Wn2[(qk * 8 + j) * 128 + n];
  }
}

__global__ __launch_bounds__(256) void convert_h(const float* __restrict__ h, f16* __restrict__ h16) {
  int i = blockIdx.x * 256 + threadIdx.x;   // 800000 threads, 8 elems each
  const float4* src = (const float4*)h + (size_t)i * 2;
  float4 a = src[0], b = src[1];
  half8 v = {(f16)a.x, (f16)a.y, (f16)a.z, (f16)a.w,
             (f16)b.x, (f16)b.y, (f16)b.z, (f16)b.w};
  *((half8*)h16 + i) = v;
}

__global__ __launch_bounds__(256) void edge_kernel(
    const f16* __restrict__ h16, const int* __restrict__ eidx,
    const float* __restrict__ eattr,
    const f16* __restrict__ Bp1, const float* __restrict__ be1,
    const f16* __restrict__ Bp2, const float* __restrict__ be2,
    const float* __restrict__ Wg, const float* __restrict__ bg,
    float* __restrict__ mi) {
  __shared__ f16 X[64 * XS];
  __shared__ f16 T[64 * TS];
  __shared__ float part[64 * 4];
  __shared__ float eijL[64];
  __shared__ int dstL[64];
  int t = threadIdx.x;
  int e0 = blockIdx.x * 64;

  if (t < 64) dstL[t] = eidx[e0 + t];
  // ---- stage X: h[dst] (cols 0..127), h[src] (cols 128..255), 16B lanes ----
  {
    int rb = t >> 4, ch = t & 15;
    for (int p = 0; p < 4; ++p) {
      int r = p * 16 + rb;
      int d = eidx[e0 + r];
      int s = eidx[N_EDGES + e0 + r];
      *(uint4*)&X[r * XS + ch * 8]       = *(const uint4*)(h16 + (size_t)d * HID + ch * 8);
      *(uint4*)&X[r * XS + 128 + ch * 8] = *(const uint4*)(h16 + (size_t)s * HID + ch * 8);
    }
  }
  // ---- stage edge_attr (cols 256..279): 384 float4 chunks, 6 per edge ----
  for (int i = t; i < 384; i += 256) {
    int e = i / 6, kk = (i % 6) * 4;
    float4 f = *(const float4*)(eattr + (size_t)e0 * 24 + (size_t)i * 4);
    half4 hv = {(f16)f.x, (f16)f.y, (f16)f.z, (f16)f.w};
    *(half4*)&X[e * XS + 256 + kk] = hv;
  }
  if (t < 64) { uint4 z = {0, 0, 0, 0}; *(uint4*)&X[t * XS + 280] = z; } // K-pad 280..287
  __syncthreads();

  int w = t >> 6, lane = t & 63, q = lane >> 4, c = lane & 15;
  int colBase = w * 32;   // wave owns 32 output cols (2 n-tiles), all 64 edges (4 m-tiles)

  // ---- layer 1: X[64x288] @ We1[288x128] ----
  f32x4 acc[4][2];
  {
    float b0 = be1[colBase + c], b1 = be1[colBase + 16 + c];
    for (int mt = 0; mt < 4; ++mt) {
      acc[mt][0] = (f32x4){b0, b0, b0, b0};
      acc[mt][1] = (f32x4){b1, b1, b1, b1};
    }
  }
  for (int ks = 0; ks < 9; ++ks) {
    half8 bf0 = *(const half8*)(Bp1 + ((size_t)((ks * 4 + q) * 128 + colBase + c)) * 8);
    half8 bf1 = *(const half8*)(Bp1 + ((size_t)((ks * 4 + q) * 128 + colBase + 16 + c)) * 8);
    for (int mt = 0; mt < 4; ++mt) {
      half8 a = *(const half8*)&X[(mt * 16 + c) * XS + ks * 32 + q * 8];
      acc[mt][0] = __builtin_amdgcn_mfma_f32_16x16x32_f16(a, bf0, acc[mt][0], 0, 0, 0);
      acc[mt][1] = __builtin_amdgcn_mfma_f32_16x16x32_f16(a, bf1, acc[mt][1], 0, 0, 0);
    }
  }
  // relu -> T (C layout: row = q*4+r, col = lane&15)
  for (int mt = 0; mt < 4; ++mt)
    for (int nt = 0; nt < 2; ++nt)
      for (int r = 0; r < 4; ++r) {
        float v = acc[mt][nt][r];
        T[(mt * 16 + q * 4 + r) * TS + colBase + nt * 16 + c] = (f16)(v > 0.f ? v : 0.f);
      }
  __syncthreads();

  // ---- layer 2: T[64x128] @ We2[128x128] ----
  f32x4 m2[4][2];
  {
    float b0 = be2[colBase + c], b1 = be2[colBase + 16 + c];
    for (int mt = 0; mt < 4; ++mt) {
      m2[mt][0] = (f32x4){b0, b0, b0, b0};
      m2[mt][1] = (f32x4){b1, b1, b1, b1};
    }
  }
  for (int kk = 0; kk < 4; ++kk) {
    half8 bf0 = *(const half8*)(Bp2 + ((size_t)((kk * 4 + q) * 128 + colBase + c)) * 8);
    half8 bf1 = *(const half8*)(Bp2 + ((size_t)((kk * 4 + q) * 128 + colBase + 16 + c)) * 8);
    for (int mt = 0; mt < 4; ++mt) {
      half8 a = *(const half8*)&T[(mt * 16 + c) * TS + kk * 32 + q * 8];
      m2[mt][0] = __builtin_amdgcn_mfma_f32_16x16x32_f16(a, bf0, m2[mt][0], 0, 0, 0);
      m2[mt][1] = __builtin_amdgcn_mfma_f32_16x16x32_f16(a, bf1, m2[mt][1], 0, 0, 0);
    }
  }
  // ---- relu (in place) + gate partial dot over this wave's 32 cols ----
  float wg0 = Wg[colBase + c], wg1 = Wg[colBase + 16 + c];
  float pd[4][4];
  for (int mt = 0; mt < 4; ++mt)
    for (int r = 0; r < 4; ++r) {
      float v0 = m2[mt][0][r]; v0 = v0 > 0.f ? v0 : 0.f; m2[mt][0][r] = v0;
      float v1 = m2[mt][1][r]; v1 = v1 > 0.f ? v1 : 0.f; m2[mt][1][r] = v1;
      pd[mt][r] = v0 * wg0 + v1 * wg1;
    }
  for (int off = 1; off < 16; off <<= 1)
    for (int mt = 0; mt < 4; ++mt)
      for (int r = 0; r < 4; ++r)
        pd[mt][r] += __shfl_xor(pd[mt][r], off, 64);
  if (c == 0)
    for (int mt = 0; mt < 4; ++mt)
      for (int r = 0; r < 4; ++r)
        part[(mt * 16 + q * 4 + r) * 4 + w] = pd[mt][r];
  __syncthreads();
  if (t < 64) {
    float s = part[t * 4] + part[t * 4 + 1] + part[t * 4 + 2] + part[t * 4 + 3] + bg[0];
    eijL[t] = 1.f / (1.f + __expf(-s));
  }
  __syncthreads();

  // ---- scatter-add mij*eij into mi[dst] ----
  for (int mt = 0; mt < 4; ++mt)
    for (int r = 0; r < 4; ++r) {
      int el = mt * 16 + q * 4 + r;
      float ev = eijL[el];
      float* base = mi + (size_t)dstL[el] * HID + colBase + c;
      atomicAdd(base,      m2[mt][0][r] * ev);
      atomicAdd(base + 16, m2[mt][1][r] * ev);
    }
}

__global__ __launch_bounds__(256) void node_kernel(
    const float* __restrict__ mi, const f16* __restrict__ h16,
    const f16* __restrict__ BN1, const float* __restrict__ bn1,
    const f16* __restrict__ BN2, const float* __restrict__ bn2,
    float* __restrict__ out) {
  __shared__ f16 Y[64 * YS];
  __shared__ f16 T[64 * TS];
  int t = threadIdx.x;
  int n0 = blockIdx.x * 64;
  {
    int rb = t >> 4, ch = t & 15;
    for (int p = 0; p < 4; ++p) {
      int r = p * 16 + rb;
      int g = n0 + r; if (g >= N_NODES) g = N_NODES - 1;
      const float4* s = (const float4*)(mi + (size_t)g * HID + ch * 8);
      float4 a = s[0], b = s[1];
      half8 v = {(f16)a.x, (f16)a.y, (f16)a.z, (f16)a.w,
                 (f16)b.x, (f16)b.y, (f16)b.z, (f16)b.w};
      *(half8*)&Y[r * YS + ch * 8] = v;
      *(uint4*)&Y[r * YS + 128 + ch * 8] = *(const uint4*)(h16 + (size_t)g * HID + ch * 8);
    }
  }
  __syncthreads();

  int w = t >> 6, lane = t & 63, q = lane >> 4, c = lane & 15;
  int colBase = w * 32;

  f32x4 acc[4][2];
  {
    float b0 = bn1[colBase + c], b1 = bn1[colBase + 16 + c];
    for (int mt = 0; mt < 4; ++mt) {
      acc[mt][0] = (f32x4){b0, b0, b0, b0};
      acc[mt][1] = (f32x4){b1, b1, b1, b1};
    }
  }
  for (int ks = 0; ks < 8; ++ks) {
    half8 bf0 = *(const half8*)(BN1 + ((size_t)((ks * 4 + q) * 128 + colBase + c)) * 8);
    half8 bf1 = *(const half8*)(BN1 + ((size_t)((ks * 4 + q) * 128 + colBase + 16 + c)) * 8);
    for (int mt = 0; mt < 4; ++mt) {
      half8 a = *(const half8*)&Y[(mt * 16 + c) * YS + ks * 32 + q * 8];
      acc[mt][0] = __builtin_amdgcn_mfma_f32_16x16x32_f16(a, bf0, acc[mt][0], 0, 0, 0);
      acc[mt][1] = __builtin_amdgcn_mfma_f32_16x16x32_f16(a, bf1, acc[mt][1], 0, 0, 0);
    }
  }
  for (int mt = 0; mt < 4; ++mt)
    for (int nt = 0; nt < 2; ++nt)
      for (int r = 0; r < 4; ++r) {
        float v = acc[mt][nt][r];
        T[(mt * 16 + q * 4 + r) * TS + colBase + nt * 16 + c] = (f16)(v > 0.f ? v : 0.f);
      }
  __syncthreads();

  f32x4 m2[4][2];
  {
    float b0 = bn2[colBase + c], b1 = bn2[colBase + 16 + c];
    for (int mt = 0; mt < 4; ++mt) {
      m2[mt][0] = (f32x4){b0, b0, b0, b0};
      m2[mt][1] = (f32x4){b1, b1, b1, b1};
    }
  }
  for (int kk = 0; kk < 4; ++kk) {
    half8 bf0 = *(const half8*)(BN2 + ((size_t)((kk * 4 + q) * 128 + colBase + c)) * 8);
    half8 bf1 = *(const half8*)(BN2 + ((size_t)((kk * 4 + q) * 128 + colBase + 16 + c)) * 8);
    for (int mt = 0; mt < 4; ++mt) {
      half8 a = *(const half8*)&T[(mt * 16 + c) * TS + kk * 32 + q * 8];
      m2[mt][0] = __builtin_amdgcn_mfma_f32_16x16x32_f16(a, bf0, m2[mt][0], 0, 0, 0);
      m2[mt][1] = __builtin_amdgcn_mfma_f32_16x16x32_f16(a, bf1, m2[mt][1], 0, 0, 0);
    }
  }
  for (int mt = 0; mt < 4; ++mt)
    for (int r = 0; r < 4; ++r) {
      int g = n0 + mt * 16 + q * 4 + r;
      if (g < N_NODES) {
        float* o = out + (size_t)g * HID + colBase + c;
        o[0]  = m2[mt][0][r];
        o[16] = m2[mt][1][r];
      }
    }
}

extern "C" void kernel_launch(void* const* d_in, const int* in_sizes, int n_in,
                              void* d_out, int out_size, void* d_ws, size_t ws_size,
                              hipStream_t stream) {
  const float* h    = (const float*)d_in[0];
  const int*   eidx = (const int*)d_in[1];
  const float* eattr= (const float*)d_in[2];
  const float* We1  = (const float*)d_in[3];
  const float* be1  = (const float*)d_in[4];
  const float* We2  = (const float*)d_in[5];
  const float* be2  = (const float*)d_in[6];
  const float* Wg   = (const float*)d_in[7];
  const float* bg   = (const float*)d_in[8];
  const float* Wn1  = (const float*)d_in[9];
  const float* bn1  = (const float*)d_in[10];
  const float* Wn2  = (const float*)d_in[11];
  const float* bn2  = (const float*)d_in[12];
  float* out = (float*)d_out;

  char* ws = (char*)d_ws;
  float* mi  = (float*)(ws + OFF_MI);
  f16*   h16 = (f16*)(ws + OFF_H16);
  f16*   Bp1 = (f16*)(ws + OFF_BP1);
  f16*   Bp2 = (f16*)(ws + OFF_BP2);
  f16*   BN1 = (f16*)(ws + OFF_BN1);
  f16*   BN2 = (f16*)(ws + OFF_BN2);

  hipMemsetAsync(mi, 0, (size_t)N_NODES * HID * sizeof(float), stream);
  pack_weights<<<400, 256, 0, stream>>>(We1, We2, Wn1, Wn2, Bp1, Bp2, BN1, BN2);
  convert_h<<<3125, 256, 0, stream>>>(h, h16);
  edge_kernel<<<N_EDGES / 64, 256, 0, stream>>>(h16, eidx, eattr, Bp1, be1, Bp2, be2, Wg, bg, mi);
  node_kernel<<<(N_NODES + 63) / 64, 256, 0, stream>>>(mi, h16, BN1, bn1, BN2, bn2, out);
}

// Round 2
// 529.590 us; speedup vs baseline: 1.0998x; 1.0998x over previous
//
#include <hip/hip_runtime.h>

#define N_NODES 50000
#define N_EDGES 800000
#define HID 128

typedef _Float16 f16;
typedef _Float16 half8 __attribute__((ext_vector_type(8)));
typedef _Float16 half4 __attribute__((ext_vector_type(4)));
typedef float f32x4 __attribute__((ext_vector_type(4)));

// ---- workspace layout (bytes) ----
#define OFF_MI   0UL                 // 50000*128*4  = 25,600,000
#define OFF_H16  25600000UL          // 50000*128*2  = 12,800,000
#define OFF_BP1  38400000UL          // 9*4*128*8*2  = 73,728
#define OFF_BP2  38473728UL          // 4*4*128*8*2  = 32,768
#define OFF_BN1  38506496UL          // 8*4*128*8*2  = 65,536
#define OFF_BN2  38572032UL          // 32,768      -> total 38,604,800

#define XS 296   // X tile stride (f16): 128 hdst | 128 hsrc | 24 attr | 8 zero | 8 unused
#define TS 136   // T tile stride (aliased into X buffer)
#define YS 264   // node Y tile stride (256 + pad)

__global__ __launch_bounds__(256) void pack_weights(
    const float* __restrict__ We1, const float* __restrict__ We2,
    const float* __restrict__ Wn1, const float* __restrict__ Wn2,
    f16* __restrict__ Bp1, f16* __restrict__ Bp2,
    f16* __restrict__ BN1, f16* __restrict__ BN2) {
  int i = blockIdx.x * 256 + threadIdx.x;   // 0..102399
  if (i < 36864) {                          // We1: 9 ksteps (rows permuted: h first, attr last)
    int j = i & 7, n = (i >> 3) & 127, qk = i >> 10;
    int k = qk * 8 + j;
    float v = 0.f;
    if (k < 256) v = We1[(24 + k) * 128 + n];
    else if (k < 280) v = We1[(k - 256) * 128 + n];
    Bp1[i] = (f16)v;
  } else if (i < 53248) {                   // We2: 4 ksteps
    int l = i - 36864;
    int j = l & 7, n = (l >> 3) & 127, qk = l >> 10;
    Bp2[l] = (f16)We2[(qk * 8 + j) * 128 + n];
  } else if (i < 86016) {                   // Wn1: 8 ksteps
    int l = i - 53248;
    int j = l & 7, n = (l >> 3) & 127, qk = l >> 10;
    BN1[l] = (f16)Wn1[(qk * 8 + j) * 128 + n];
  } else if (i < 102400) {                  // Wn2: 4 ksteps
    int l = i - 86016;
    int j = l & 7, n = (l >> 3) & 127, qk = l >> 10;
    BN2[l] = (f16)Wn2[(qk * 8 + j) * 128 + n];
  }
}

__global__ __launch_bounds__(256) void convert_h(const float* __restrict__ h, f16* __restrict__ h16) {
  int i = blockIdx.x * 256 + threadIdx.x;
  const float4* src = (const float4*)h + (size_t)i * 2;
  float4 a = src[0], b = src[1];
  half8 v = {(f16)a.x, (f16)a.y, (f16)a.z, (f16)a.w,
             (f16)b.x, (f16)b.y, (f16)b.z, (f16)b.w};
  *((half8*)h16 + i) = v;
}

// LDS: X(37,888) aliased by T + part(1024) + eijL(256) + dstL(256) = 39,424 B -> 4 blocks/CU
__global__ __launch_bounds__(256, 4) void edge_kernel(
    const f16* __restrict__ h16, const int* __restrict__ eidx,
    const float* __restrict__ eattr,
    const f16* __restrict__ Bp1, const float* __restrict__ be1,
    const f16* __restrict__ Bp2, const float* __restrict__ be2,
    const float* __restrict__ Wg, const float* __restrict__ bg,
    float* __restrict__ mi) {
  __shared__ f16 X[64 * XS];
  __shared__ float part[64 * 4];
  __shared__ float eijL[64];
  __shared__ int dstL[64];
  int t = threadIdx.x;
  int e0 = blockIdx.x * 64;

  if (t < 64) dstL[t] = eidx[e0 + t];
  // ---- stage X: h[dst] (cols 0..127), h[src] (cols 128..255) ----
  {
    int rb = t >> 4, ch = t & 15;
    for (int p = 0; p < 4; ++p) {
      int r = p * 16 + rb;
      int d = eidx[e0 + r];
      int s = eidx[N_EDGES + e0 + r];
      *(uint4*)&X[r * XS + ch * 8]       = *(const uint4*)(h16 + (size_t)d * HID + ch * 8);
      *(uint4*)&X[r * XS + 128 + ch * 8] = *(const uint4*)(h16 + (size_t)s * HID + ch * 8);
    }
  }
  // ---- stage edge_attr (cols 256..279) ----
  for (int i = t; i < 384; i += 256) {
    int e = i / 6, kk = (i % 6) * 4;
    float4 f = *(const float4*)(eattr + (size_t)e0 * 24 + (size_t)i * 4);
    half4 hv = {(f16)f.x, (f16)f.y, (f16)f.z, (f16)f.w};
    *(half4*)&X[e * XS + 256 + kk] = hv;
  }
  if (t < 64) { uint4 z = {0, 0, 0, 0}; *(uint4*)&X[t * XS + 280] = z; }
  __syncthreads();

  int w = t >> 6, lane = t & 63, q = lane >> 4, c = lane & 15;
  int colBase = w * 32;

  // ---- layer 1: X[64x288] @ We1[288x128], B-frag loads software-pipelined ----
  f32x4 acc[4][2];
  {
    float b0 = be1[colBase + c], b1 = be1[colBase + 16 + c];
    #pragma unroll
    for (int mt = 0; mt < 4; ++mt) {
      acc[mt][0] = (f32x4){b0, b0, b0, b0};
      acc[mt][1] = (f32x4){b1, b1, b1, b1};
    }
  }
  const f16* bp1base = Bp1 + ((size_t)(q * 128 + colBase + c)) * 8;  // +ks*4096, +128 for n-tile 1
  half8 bf0 = *(const half8*)(bp1base);
  half8 bf1 = *(const half8*)(bp1base + 128);
  #pragma unroll
  for (int ks = 0; ks < 9; ++ks) {
    half8 nb0, nb1;
    if (ks < 8) {
      nb0 = *(const half8*)(bp1base + (ks + 1) * 4096);
      nb1 = *(const half8*)(bp1base + (ks + 1) * 4096 + 128);
    }
    #pragma unroll
    for (int mt = 0; mt < 4; ++mt) {
      half8 a = *(const half8*)&X[(mt * 16 + c) * XS + ks * 32 + q * 8];
      acc[mt][0] = __builtin_amdgcn_mfma_f32_16x16x32_f16(a, bf0, acc[mt][0], 0, 0, 0);
      acc[mt][1] = __builtin_amdgcn_mfma_f32_16x16x32_f16(a, bf1, acc[mt][1], 0, 0, 0);
    }
    bf0 = nb0; bf1 = nb1;
  }

  // prefetch layer-2 kk=0 B-frags while waiting at the barrier
  const f16* bp2base = Bp2 + ((size_t)(q * 128 + colBase + c)) * 8;
  half8 d0 = *(const half8*)(bp2base);
  half8 d1 = *(const half8*)(bp2base + 128);

  __syncthreads();               // all layer-1 X reads complete
  f16* T = X;                    // alias T into X's LDS
  #pragma unroll
  for (int mt = 0; mt < 4; ++mt)
    #pragma unroll
    for (int nt = 0; nt < 2; ++nt)
      #pragma unroll
      for (int r = 0; r < 4; ++r) {
        float v = acc[mt][nt][r];
        T[(mt * 16 + q * 4 + r) * TS + colBase + nt * 16 + c] = (f16)(v > 0.f ? v : 0.f);
      }
  __syncthreads();

  // ---- layer 2: T[64x128] @ We2[128x128] ----
  f32x4 m2[4][2];
  {
    float b0 = be2[colBase + c], b1 = be2[colBase + 16 + c];
    #pragma unroll
    for (int mt = 0; mt < 4; ++mt) {
      m2[mt][0] = (f32x4){b0, b0, b0, b0};
      m2[mt][1] = (f32x4){b1, b1, b1, b1};
    }
  }
  #pragma unroll
  for (int kk = 0; kk < 4; ++kk) {
    half8 n0, n1;
    if (kk < 3) {
      n0 = *(const half8*)(bp2base + (kk + 1) * 4096);
      n1 = *(const half8*)(bp2base + (kk + 1) * 4096 + 128);
    }
    #pragma unroll
    for (int mt = 0; mt < 4; ++mt) {
      half8 a = *(const half8*)&T[(mt * 16 + c) * TS + kk * 32 + q * 8];
      m2[mt][0] = __builtin_amdgcn_mfma_f32_16x16x32_f16(a, d0, m2[mt][0], 0, 0, 0);
      m2[mt][1] = __builtin_amdgcn_mfma_f32_16x16x32_f16(a, d1, m2[mt][1], 0, 0, 0);
    }
    d0 = n0; d1 = n1;
  }

  // ---- relu + gate partial dot ----
  float wg0 = Wg[colBase + c], wg1 = Wg[colBase + 16 + c];
  float pd[4][4];
  #pragma unroll
  for (int mt = 0; mt < 4; ++mt)
    #pragma unroll
    for (int r = 0; r < 4; ++r) {
      float v0 = m2[mt][0][r]; v0 = v0 > 0.f ? v0 : 0.f; m2[mt][0][r] = v0;
      float v1 = m2[mt][1][r]; v1 = v1 > 0.f ? v1 : 0.f; m2[mt][1][r] = v1;
      pd[mt][r] = v0 * wg0 + v1 * wg1;
    }
  #pragma unroll
  for (int off = 1; off < 16; off <<= 1)
    #pragma unroll
    for (int mt = 0; mt < 4; ++mt)
      #pragma unroll
      for (int r = 0; r < 4; ++r)
        pd[mt][r] += __shfl_xor(pd[mt][r], off, 64);
  if (c == 0)
    #pragma unroll
    for (int mt = 0; mt < 4; ++mt)
      #pragma unroll
      for (int r = 0; r < 4; ++r)
        part[(mt * 16 + q * 4 + r) * 4 + w] = pd[mt][r];
  __syncthreads();
  if (t < 64) {
    float s = part[t * 4] + part[t * 4 + 1] + part[t * 4 + 2] + part[t * 4 + 3] + bg[0];
    eijL[t] = 1.f / (1.f + __expf(-s));
  }
  __syncthreads();

  // ---- scatter-add mij*eij into mi[dst] ----
  #pragma unroll
  for (int mt = 0; mt < 4; ++mt)
    #pragma unroll
    for (int r = 0; r < 4; ++r) {
      int el = mt * 16 + q * 4 + r;
      float ev = eijL[el];
      float* base = mi + (size_t)dstL[el] * HID + colBase + c;
      atomicAdd(base,      m2[mt][0][r] * ev);
      atomicAdd(base + 16, m2[mt][1][r] * ev);
    }
}

// LDS: Y(33,792) aliased by T -> 4+ blocks/CU
__global__ __launch_bounds__(256, 4) void node_kernel(
    const float* __restrict__ mi, const f16* __restrict__ h16,
    const f16* __restrict__ BN1, const float* __restrict__ bn1,
    const f16* __restrict__ BN2, const float* __restrict__ bn2,
    float* __restrict__ out) {
  __shared__ f16 Y[64 * YS];
  int t = threadIdx.x;
  int n0 = blockIdx.x * 64;
  {
    int rb = t >> 4, ch = t & 15;
    for (int p = 0; p < 4; ++p) {
      int r = p * 16 + rb;
      int g = n0 + r; if (g >= N_NODES) g = N_NODES - 1;
      const float4* s = (const float4*)(mi + (size_t)g * HID + ch * 8);
      float4 a = s[0], b = s[1];
      half8 v = {(f16)a.x, (f16)a.y, (f16)a.z, (f16)a.w,
                 (f16)b.x, (f16)b.y, (f16)b.z, (f16)b.w};
      *(half8*)&Y[r * YS + ch * 8] = v;
      *(uint4*)&Y[r * YS + 128 + ch * 8] = *(const uint4*)(h16 + (size_t)g * HID + ch * 8);
    }
  }
  __syncthreads();

  int w = t >> 6, lane = t & 63, q = lane >> 4, c = lane & 15;
  int colBase = w * 32;

  f32x4 acc[4][2];
  {
    float b0 = bn1[colBase + c], b1 = bn1[colBase + 16 + c];
    #pragma unroll
    for (int mt = 0; mt < 4; ++mt) {
      acc[mt][0] = (f32x4){b0, b0, b0, b0};
      acc[mt][1] = (f32x4){b1, b1, b1, b1};
    }
  }
  const f16* bn1base = BN1 + ((size_t)(q * 128 + colBase + c)) * 8;
  half8 bf0 = *(const half8*)(bn1base);
  half8 bf1 = *(const half8*)(bn1base + 128);
  #pragma unroll
  for (int ks = 0; ks < 8; ++ks) {
    half8 nb0, nb1;
    if (ks < 7) {
      nb0 = *(const half8*)(bn1base + (ks + 1) * 4096);
      nb1 = *(const half8*)(bn1base + (ks + 1) * 4096 + 128);
    }
    #pragma unroll
    for (int mt = 0; mt < 4; ++mt) {
      half8 a = *(const half8*)&Y[(mt * 16 + c) * YS + ks * 32 + q * 8];
      acc[mt][0] = __builtin_amdgcn_mfma_f32_16x16x32_f16(a, bf0, acc[mt][0], 0, 0, 0);
      acc[mt][1] = __builtin_amdgcn_mfma_f32_16x16x32_f16(a, bf1, acc[mt][1], 0, 0, 0);
    }
    bf0 = nb0; bf1 = nb1;
  }

  const f16* bn2base = BN2 + ((size_t)(q * 128 + colBase + c)) * 8;
  half8 d0 = *(const half8*)(bn2base);
  half8 d1 = *(const half8*)(bn2base + 128);

  __syncthreads();
  f16* T = Y;                    // alias
  #pragma unroll
  for (int mt = 0; mt < 4; ++mt)
    #pragma unroll
    for (int nt = 0; nt < 2; ++nt)
      #pragma unroll
      for (int r = 0; r < 4; ++r) {
        float v = acc[mt][nt][r];
        T[(mt * 16 + q * 4 + r) * TS + colBase + nt * 16 + c] = (f16)(v > 0.f ? v : 0.f);
      }
  __syncthreads();

  f32x4 m2[4][2];
  {
    float b0 = bn2[colBase + c], b1 = bn2[colBase + 16 + c];
    #pragma unroll
    for (int mt = 0; mt < 4; ++mt) {
      m2[mt][0] = (f32x4){b0, b0, b0, b0};
      m2[mt][1] = (f32x4){b1, b1, b1, b1};
    }
  }
  #pragma unroll
  for (int kk = 0; kk < 4; ++kk) {
    half8 n0, n1;
    if (kk < 3) {
      n0 = *(const half8*)(bn2base + (kk + 1) * 4096);
      n1 = *(const half8*)(bn2base + (kk + 1) * 4096 + 128);
    }
    #pragma unroll
    for (int mt = 0; mt < 4; ++mt) {
      half8 a = *(const half8*)&T[(mt * 16 + c) * TS + kk * 32 + q * 8];
      m2[mt][0] = __builtin_amdgcn_mfma_f32_16x16x32_f16(a, d0, m2[mt][0], 0, 0, 0);
      m2[mt][1] = __builtin_amdgcn_mfma_f32_16x16x32_f16(a, d1, m2[mt][1], 0, 0, 0);
    }
    d0 = n0; d1 = n1;
  }
  #pragma unroll
  for (int mt = 0; mt < 4; ++mt)
    #pragma unroll
    for (int r = 0; r < 4; ++r) {
      int g = n0 + mt * 16 + q * 4 + r;
      if (g < N_NODES) {
        float* o = out + (size_t)g * HID + colBase + c;
        o[0]  = m2[mt][0][r];
        o[16] = m2[mt][1][r];
      }
    }
}

extern "C" void kernel_launch(void* const* d_in, const int* in_sizes, int n_in,
                              void* d_out, int out_size, void* d_ws, size_t ws_size,
                              hipStream_t stream) {
  const float* h    = (const float*)d_in[0];
  const int*   eidx = (const int*)d_in[1];
  const float* eattr= (const float*)d_in[2];
  const float* We1  = (const float*)d_in[3];
  const float* be1  = (const float*)d_in[4];
  const float* We2  = (const float*)d_in[5];
  const float* be2  = (const float*)d_in[6];
  const float* Wg   = (const float*)d_in[7];
  const float* bg   = (const float*)d_in[8];
  const float* Wn1  = (const float*)d_in[9];
  const float* bn1  = (const float*)d_in[10];
  const float* Wn2  = (const float*)d_in[11];
  const float* bn2  = (const float*)d_in[12];
  float* out = (float*)d_out;

  char* ws = (char*)d_ws;
  float* mi  = (float*)(ws + OFF_MI);
  f16*   h16 = (f16*)(ws + OFF_H16);
  f16*   Bp1 = (f16*)(ws + OFF_BP1);
  f16*   Bp2 = (f16*)(ws + OFF_BP2);
  f16*   BN1 = (f16*)(ws + OFF_BN1);
  f16*   BN2 = (f16*)(ws + OFF_BN2);

  hipMemsetAsync(mi, 0, (size_t)N_NODES * HID * sizeof(float), stream);
  pack_weights<<<400, 256, 0, stream>>>(We1, We2, Wn1, Wn2, Bp1, Bp2, BN1, BN2);
  convert_h<<<3125, 256, 0, stream>>>(h, h16);
  edge_kernel<<<N_EDGES / 64, 256, 0, stream>>>(h16, eidx, eattr, Bp1, be1, Bp2, be2, Wg, bg, mi);
  node_kernel<<<(N_NODES + 63) / 64, 256, 0, stream>>>(mi, h16, BN1, bn1, BN2, bn2, out);
}

// Round 3
// 483.742 us; speedup vs baseline: 1.2040x; 1.0948x over previous
//
#include <hip/hip_runtime.h>

#define N_NODES 50000
#define N_EDGES 800000
#define HID 128

typedef _Float16 f16;
typedef _Float16 half8 __attribute__((ext_vector_type(8)));
typedef _Float16 half4 __attribute__((ext_vector_type(4)));
typedef float f32x4 __attribute__((ext_vector_type(4)));

// ---- CSR-path workspace layout (bytes) ----
#define OFF_MEDGE  0UL             // 800000*128*2 = 204,800,000
#define OFF_H16C   204800000UL     // 12,800,000
#define OFF_WC     217600000UL     // packed weights: 73728+32768+65536+32768 = 204,800
#define OFF_CNT    217804800UL     // 50176*4 = 200,704
#define OFF_OFFS   218005504UL     // 200,704
#define OFF_CUR    218206208UL     // 200,704
#define OFF_BSUM   218406912UL     // 1,024
#define OFF_ELIST  218407936UL     // 3,200,000
#define CSR_TOTAL  221607936UL

// ---- fallback (atomic-path) layout ----
#define OFF_MI   0UL
#define OFF_H16  25600000UL
#define OFF_W    38400000UL

#define WB1 0       // Bp1 offset within weight block (f16 elems)
#define WB2 36864
#define WN1 53248
#define WN2 86016

#define XS 296   // X tile stride (f16): 128 hdst | 128 hsrc | 24 attr | 8 zero | 8 unused
#define TS 136   // T tile stride (aliased into X buffer)
#define YS 264   // node Y tile stride (256 + pad)

__global__ __launch_bounds__(256) void pack_weights(
    const float* __restrict__ We1, const float* __restrict__ We2,
    const float* __restrict__ Wn1, const float* __restrict__ Wn2,
    f16* __restrict__ W) {
  int i = blockIdx.x * 256 + threadIdx.x;   // 0..102399
  if (i < 36864) {                          // We1: 9 ksteps (rows permuted: h first, attr last)
    int j = i & 7, n = (i >> 3) & 127, qk = i >> 10;
    int k = qk * 8 + j;
    float v = 0.f;
    if (k < 256) v = We1[(24 + k) * 128 + n];
    else if (k < 280) v = We1[(k - 256) * 128 + n];
    W[WB1 + i] = (f16)v;
  } else if (i < 53248) {                   // We2
    int l = i - 36864;
    int j = l & 7, n = (l >> 3) & 127, qk = l >> 10;
    W[WB2 + l] = (f16)We2[(qk * 8 + j) * 128 + n];
  } else if (i < 86016) {                   // Wn1
    int l = i - 53248;
    int j = l & 7, n = (l >> 3) & 127, qk = l >> 10;
    W[WN1 + l] = (f16)Wn1[(qk * 8 + j) * 128 + n];
  } else if (i < 102400) {                  // Wn2
    int l = i - 86016;
    int j = l & 7, n = (l >> 3) & 127, qk = l >> 10;
    W[WN2 + l] = (f16)Wn2[(qk * 8 + j) * 128 + n];
  }
}

__global__ __launch_bounds__(256) void convert_h(const float* __restrict__ h, f16* __restrict__ h16) {
  int i = blockIdx.x * 256 + threadIdx.x;
  const float4* src = (const float4*)h + (size_t)i * 2;
  float4 a = src[0], b = src[1];
  half8 v = {(f16)a.x, (f16)a.y, (f16)a.z, (f16)a.w,
             (f16)b.x, (f16)b.y, (f16)b.z, (f16)b.w};
  *((half8*)h16 + i) = v;
}

// ==== CSR build ====
__global__ __launch_bounds__(256) void hist_kernel(const int* __restrict__ eidx, int* __restrict__ cnt) {
  int e = blockIdx.x * 256 + threadIdx.x;
  if (e < N_EDGES) atomicAdd(&cnt[eidx[e]], 1);
}

// 49 blocks x 256 threads, 1024 elements/block: local exclusive scan -> offs, block total -> bsum
__global__ __launch_bounds__(256) void scan1_kernel(const int* __restrict__ cnt,
                                                    int* __restrict__ offs, int* __restrict__ bsum) {
  __shared__ int sb[256];
  int t = threadIdx.x, base = blockIdx.x * 1024;
  int c[4];
  int s4 = 0;
  #pragma unroll
  for (int k = 0; k < 4; ++k) { c[k] = cnt[base + t * 4 + k]; s4 += c[k]; }
  sb[t] = s4;
  __syncthreads();
  for (int off = 1; off < 256; off <<= 1) {
    int v = 0;
    if (t >= off) v = sb[t - off];
    __syncthreads();
    sb[t] += v;
    __syncthreads();
  }
  int run = sb[t] - s4;   // exclusive prefix of this thread's chunk
  #pragma unroll
  for (int k = 0; k < 4; ++k) { offs[base + t * 4 + k] = run; run += c[k]; }
  if (t == 255) bsum[blockIdx.x] = sb[255];
}

// 196 blocks x 256: add global base per 1024-chunk; cursor := offs
__global__ __launch_bounds__(256) void scan2_kernel(int* __restrict__ offs, int* __restrict__ cur,
                                                    const int* __restrict__ bsum) {
  __shared__ int baseS;
  int t = threadIdx.x;
  int i = blockIdx.x * 256 + t;
  int chunk = blockIdx.x >> 2;
  if (t == 0) {
    int s = 0;
    for (int j = 0; j < chunk; ++j) s += bsum[j];
    baseS = s;
  }
  __syncthreads();
  int v = offs[i] + baseS;
  offs[i] = v;
  cur[i] = v;
}

__global__ __launch_bounds__(256) void scatter_kernel(const int* __restrict__ eidx,
                                                      int* __restrict__ cur, int* __restrict__ elist) {
  int e = blockIdx.x * 256 + threadIdx.x;
  if (e < N_EDGES) {
    int p = atomicAdd(&cur[eidx[e]], 1);
    elist[p] = e;
  }
}

// ==== edge kernel: 64 edges/block; epilogue = CSR store (medge!=0) or atomic (fallback) ====
__global__ __launch_bounds__(256, 4) void edge_kernel(
    const f16* __restrict__ h16, const int* __restrict__ eidx,
    const float* __restrict__ eattr,
    const f16* __restrict__ Wp, const float* __restrict__ be1,
    const float* __restrict__ be2,
    const float* __restrict__ Wg, const float* __restrict__ bg,
    float* __restrict__ mi, f16* __restrict__ medge) {
  __shared__ f16 X[64 * XS];
  __shared__ float part[64 * 4];
  __shared__ float eijL[64];
  __shared__ int dstL[64];
  int t = threadIdx.x;
  int e0 = blockIdx.x * 64;

  if (!medge && t < 64) dstL[t] = eidx[e0 + t];
  {
    int rb = t >> 4, ch = t & 15;
    for (int p = 0; p < 4; ++p) {
      int r = p * 16 + rb;
      int d = eidx[e0 + r];
      int s = eidx[N_EDGES + e0 + r];
      *(uint4*)&X[r * XS + ch * 8]       = *(const uint4*)(h16 + (size_t)d * HID + ch * 8);
      *(uint4*)&X[r * XS + 128 + ch * 8] = *(const uint4*)(h16 + (size_t)s * HID + ch * 8);
    }
  }
  for (int i = t; i < 384; i += 256) {
    int e = i / 6, kk = (i % 6) * 4;
    float4 f = *(const float4*)(eattr + (size_t)e0 * 24 + (size_t)i * 4);
    half4 hv = {(f16)f.x, (f16)f.y, (f16)f.z, (f16)f.w};
    *(half4*)&X[e * XS + 256 + kk] = hv;
  }
  if (t < 64) { uint4 z = {0, 0, 0, 0}; *(uint4*)&X[t * XS + 280] = z; }
  __syncthreads();

  int w = t >> 6, lane = t & 63, q = lane >> 4, c = lane & 15;
  int colBase = w * 32;
  const f16* Bp1 = Wp + WB1;
  const f16* Bp2 = Wp + WB2;

  // ---- layer 1 ----
  f32x4 acc[4][2];
  {
    float b0 = be1[colBase + c], b1 = be1[colBase + 16 + c];
    #pragma unroll
    for (int mt = 0; mt < 4; ++mt) {
      acc[mt][0] = (f32x4){b0, b0, b0, b0};
      acc[mt][1] = (f32x4){b1, b1, b1, b1};
    }
  }
  const f16* bp1base = Bp1 + ((size_t)(q * 128 + colBase + c)) * 8;
  half8 bf0 = *(const half8*)(bp1base);
  half8 bf1 = *(const half8*)(bp1base + 128);
  #pragma unroll
  for (int ks = 0; ks < 9; ++ks) {
    half8 nb0, nb1;
    if (ks < 8) {
      nb0 = *(const half8*)(bp1base + (ks + 1) * 4096);
      nb1 = *(const half8*)(bp1base + (ks + 1) * 4096 + 128);
    }
    #pragma unroll
    for (int mt = 0; mt < 4; ++mt) {
      half8 a = *(const half8*)&X[(mt * 16 + c) * XS + ks * 32 + q * 8];
      acc[mt][0] = __builtin_amdgcn_mfma_f32_16x16x32_f16(a, bf0, acc[mt][0], 0, 0, 0);
      acc[mt][1] = __builtin_amdgcn_mfma_f32_16x16x32_f16(a, bf1, acc[mt][1], 0, 0, 0);
    }
    bf0 = nb0; bf1 = nb1;
  }

  const f16* bp2base = Bp2 + ((size_t)(q * 128 + colBase + c)) * 8;
  half8 d0 = *(const half8*)(bp2base);
  half8 d1 = *(const half8*)(bp2base + 128);

  __syncthreads();
  f16* T = X;   // alias
  #pragma unroll
  for (int mt = 0; mt < 4; ++mt)
    #pragma unroll
    for (int nt = 0; nt < 2; ++nt)
      #pragma unroll
      for (int r = 0; r < 4; ++r) {
        float v = acc[mt][nt][r];
        T[(mt * 16 + q * 4 + r) * TS + colBase + nt * 16 + c] = (f16)(v > 0.f ? v : 0.f);
      }
  __syncthreads();

  // ---- layer 2 ----
  f32x4 m2[4][2];
  {
    float b0 = be2[colBase + c], b1 = be2[colBase + 16 + c];
    #pragma unroll
    for (int mt = 0; mt < 4; ++mt) {
      m2[mt][0] = (f32x4){b0, b0, b0, b0};
      m2[mt][1] = (f32x4){b1, b1, b1, b1};
    }
  }
  #pragma unroll
  for (int kk = 0; kk < 4; ++kk) {
    half8 n0, n1;
    if (kk < 3) {
      n0 = *(const half8*)(bp2base + (kk + 1) * 4096);
      n1 = *(const half8*)(bp2base + (kk + 1) * 4096 + 128);
    }
    #pragma unroll
    for (int mt = 0; mt < 4; ++mt) {
      half8 a = *(const half8*)&T[(mt * 16 + c) * TS + kk * 32 + q * 8];
      m2[mt][0] = __builtin_amdgcn_mfma_f32_16x16x32_f16(a, d0, m2[mt][0], 0, 0, 0);
      m2[mt][1] = __builtin_amdgcn_mfma_f32_16x16x32_f16(a, d1, m2[mt][1], 0, 0, 0);
    }
    d0 = n0; d1 = n1;
  }

  // ---- relu + gate ----
  float wg0 = Wg[colBase + c], wg1 = Wg[colBase + 16 + c];
  float pd[4][4];
  #pragma unroll
  for (int mt = 0; mt < 4; ++mt)
    #pragma unroll
    for (int r = 0; r < 4; ++r) {
      float v0 = m2[mt][0][r]; v0 = v0 > 0.f ? v0 : 0.f; m2[mt][0][r] = v0;
      float v1 = m2[mt][1][r]; v1 = v1 > 0.f ? v1 : 0.f; m2[mt][1][r] = v1;
      pd[mt][r] = v0 * wg0 + v1 * wg1;
    }
  #pragma unroll
  for (int off = 1; off < 16; off <<= 1)
    #pragma unroll
    for (int mt = 0; mt < 4; ++mt)
      #pragma unroll
      for (int r = 0; r < 4; ++r)
        pd[mt][r] += __shfl_xor(pd[mt][r], off, 64);
  if (c == 0)
    #pragma unroll
    for (int mt = 0; mt < 4; ++mt)
      #pragma unroll
      for (int r = 0; r < 4; ++r)
        part[(mt * 16 + q * 4 + r) * 4 + w] = pd[mt][r];
  __syncthreads();
  if (t < 64) {
    float s = part[t * 4] + part[t * 4 + 1] + part[t * 4 + 2] + part[t * 4 + 3] + bg[0];
    eijL[t] = 1.f / (1.f + __expf(-s));
  }
  __syncthreads();

  if (medge) {
    // gated f16 -> T, then cooperative coalesced 64B-per-thread store
    #pragma unroll
    for (int mt = 0; mt < 4; ++mt)
      #pragma unroll
      for (int r = 0; r < 4; ++r) {
        int el = mt * 16 + q * 4 + r;
        float ev = eijL[el];
        T[el * TS + colBase + c]      = (f16)(m2[mt][0][r] * ev);
        T[el * TS + colBase + 16 + c] = (f16)(m2[mt][1][r] * ev);
      }
    __syncthreads();
    int r = t >> 2, p = t & 3;
    uint4* dst = (uint4*)(medge + (size_t)(e0 + r) * HID + p * 32);
    const uint4* s = (const uint4*)&T[r * TS + p * 32];
    dst[0] = s[0]; dst[1] = s[1]; dst[2] = s[2]; dst[3] = s[3];
  } else {
    #pragma unroll
    for (int mt = 0; mt < 4; ++mt)
      #pragma unroll
      for (int r = 0; r < 4; ++r) {
        int el = mt * 16 + q * 4 + r;
        float ev = eijL[el];
        float* base = mi + (size_t)dstL[el] * HID + colBase + c;
        atomicAdd(base,      m2[mt][0][r] * ev);
        atomicAdd(base + 16, m2[mt][1][r] * ev);
      }
  }
}

// ==== CSR node kernel: gather medge rows -> Y, then MLP ====
__global__ __launch_bounds__(256, 4) void node_kernel_csr(
    const f16* __restrict__ medge, const int* __restrict__ elist,
    const int* __restrict__ offs, const int* __restrict__ cnt,
    const f16* __restrict__ h16,
    const f16* __restrict__ Wp, const float* __restrict__ bn1,
    const float* __restrict__ bn2, float* __restrict__ out) {
  __shared__ f16 Y[64 * YS];
  int t = threadIdx.x;
  int n0 = blockIdx.x * 64;
  {
    int r = t >> 2, p = t & 3;
    int g = n0 + r;
    int start = 0, deg = 0;
    if (g < N_NODES) { start = offs[g]; deg = cnt[g]; } else g = N_NODES - 1;
    float a0[8] = {0,0,0,0,0,0,0,0}, a1[8] = {0,0,0,0,0,0,0,0};
    float a2[8] = {0,0,0,0,0,0,0,0}, a3[8] = {0,0,0,0,0,0,0,0};
    for (int i = 0; i < deg; ++i) {
      int e = elist[start + i];
      const half8* mp = (const half8*)(medge + (size_t)e * HID + p * 32);
      half8 v0 = mp[0], v1 = mp[1], v2 = mp[2], v3 = mp[3];
      #pragma unroll
      for (int j = 0; j < 8; ++j) {
        a0[j] += (float)v0[j]; a1[j] += (float)v1[j];
        a2[j] += (float)v2[j]; a3[j] += (float)v3[j];
      }
    }
    half8 o0, o1, o2, o3;
    #pragma unroll
    for (int j = 0; j < 8; ++j) {
      o0[j] = (f16)a0[j]; o1[j] = (f16)a1[j]; o2[j] = (f16)a2[j]; o3[j] = (f16)a3[j];
    }
    half8* yr = (half8*)&Y[r * YS + p * 32];
    yr[0] = o0; yr[1] = o1; yr[2] = o2; yr[3] = o3;
    // h cols 128..255
    const uint4* hs = (const uint4*)(h16 + (size_t)g * HID + p * 32);
    uint4* yh = (uint4*)&Y[r * YS + 128 + p * 32];
    yh[0] = hs[0]; yh[1] = hs[1]; yh[2] = hs[2]; yh[3] = hs[3];
  }
  __syncthreads();

  int w = t >> 6, lane = t & 63, q = lane >> 4, c = lane & 15;
  int colBase = w * 32;
  const f16* BN1 = Wp + WN1;
  const f16* BN2 = Wp + WN2;

  f32x4 acc[4][2];
  {
    float b0 = bn1[colBase + c], b1 = bn1[colBase + 16 + c];
    #pragma unroll
    for (int mt = 0; mt < 4; ++mt) {
      acc[mt][0] = (f32x4){b0, b0, b0, b0};
      acc[mt][1] = (f32x4){b1, b1, b1, b1};
    }
  }
  const f16* bn1base = BN1 + ((size_t)(q * 128 + colBase + c)) * 8;
  half8 bf0 = *(const half8*)(bn1base);
  half8 bf1 = *(const half8*)(bn1base + 128);
  #pragma unroll
  for (int ks = 0; ks < 8; ++ks) {
    half8 nb0, nb1;
    if (ks < 7) {
      nb0 = *(const half8*)(bn1base + (ks + 1) * 4096);
      nb1 = *(const half8*)(bn1base + (ks + 1) * 4096 + 128);
    }
    #pragma unroll
    for (int mt = 0; mt < 4; ++mt) {
      half8 a = *(const half8*)&Y[(mt * 16 + c) * YS + ks * 32 + q * 8];
      acc[mt][0] = __builtin_amdgcn_mfma_f32_16x16x32_f16(a, bf0, acc[mt][0], 0, 0, 0);
      acc[mt][1] = __builtin_amdgcn_mfma_f32_16x16x32_f16(a, bf1, acc[mt][1], 0, 0, 0);
    }
    bf0 = nb0; bf1 = nb1;
  }
  const f16* bn2base = BN2 + ((size_t)(q * 128 + colBase + c)) * 8;
  half8 d0 = *(const half8*)(bn2base);
  half8 d1 = *(const half8*)(bn2base + 128);

  __syncthreads();
  f16* T = Y;
  #pragma unroll
  for (int mt = 0; mt < 4; ++mt)
    #pragma unroll
    for (int nt = 0; nt < 2; ++nt)
      #pragma unroll
      for (int r = 0; r < 4; ++r) {
        float v = acc[mt][nt][r];
        T[(mt * 16 + q * 4 + r) * TS + colBase + nt * 16 + c] = (f16)(v > 0.f ? v : 0.f);
      }
  __syncthreads();

  f32x4 m2[4][2];
  {
    float b0 = bn2[colBase + c], b1 = bn2[colBase + 16 + c];
    #pragma unroll
    for (int mt = 0; mt < 4; ++mt) {
      m2[mt][0] = (f32x4){b0, b0, b0, b0};
      m2[mt][1] = (f32x4){b1, b1, b1, b1};
    }
  }
  #pragma unroll
  for (int kk = 0; kk < 4; ++kk) {
    half8 n0, n1;
    if (kk < 3) {
      n0 = *(const half8*)(bn2base + (kk + 1) * 4096);
      n1 = *(const half8*)(bn2base + (kk + 1) * 4096 + 128);
    }
    #pragma unroll
    for (int mt = 0; mt < 4; ++mt) {
      half8 a = *(const half8*)&T[(mt * 16 + c) * TS + kk * 32 + q * 8];
      m2[mt][0] = __builtin_amdgcn_mfma_f32_16x16x32_f16(a, d0, m2[mt][0], 0, 0, 0);
      m2[mt][1] = __builtin_amdgcn_mfma_f32_16x16x32_f16(a, d1, m2[mt][1], 0, 0, 0);
    }
    d0 = n0; d1 = n1;
  }
  #pragma unroll
  for (int mt = 0; mt < 4; ++mt)
    #pragma unroll
    for (int r = 0; r < 4; ++r) {
      int g = n0 + mt * 16 + q * 4 + r;
      if (g < N_NODES) {
        float* o = out + (size_t)g * HID + colBase + c;
        o[0]  = m2[mt][0][r];
        o[16] = m2[mt][1][r];
      }
    }
}

// ==== fallback node kernel (reads f32 mi) ====
__global__ __launch_bounds__(256, 4) void node_kernel(
    const float* __restrict__ mi, const f16* __restrict__ h16,
    const f16* __restrict__ Wp, const float* __restrict__ bn1,
    const float* __restrict__ bn2, float* __restrict__ out) {
  __shared__ f16 Y[64 * YS];
  int t = threadIdx.x;
  int n0 = blockIdx.x * 64;
  {
    int rb = t >> 4, ch = t & 15;
    for (int p = 0; p < 4; ++p) {
      int r = p * 16 + rb;
      int g = n0 + r; if (g >= N_NODES) g = N_NODES - 1;
      const float4* s = (const float4*)(mi + (size_t)g * HID + ch * 8);
      float4 a = s[0], b = s[1];
      half8 v = {(f16)a.x, (f16)a.y, (f16)a.z, (f16)a.w,
                 (f16)b.x, (f16)b.y, (f16)b.z, (f16)b.w};
      *(half8*)&Y[r * YS + ch * 8] = v;
      *(uint4*)&Y[r * YS + 128 + ch * 8] = *(const uint4*)(h16 + (size_t)g * HID + ch * 8);
    }
  }
  __syncthreads();
  int w = t >> 6, lane = t & 63, q = lane >> 4, c = lane & 15;
  int colBase = w * 32;
  const f16* BN1 = Wp + WN1;
  const f16* BN2 = Wp + WN2;
  f32x4 acc[4][2];
  {
    float b0 = bn1[colBase + c], b1 = bn1[colBase + 16 + c];
    #pragma unroll
    for (int mt = 0; mt < 4; ++mt) {
      acc[mt][0] = (f32x4){b0, b0, b0, b0};
      acc[mt][1] = (f32x4){b1, b1, b1, b1};
    }
  }
  const f16* bn1base = BN1 + ((size_t)(q * 128 + colBase + c)) * 8;
  half8 bf0 = *(const half8*)(bn1base);
  half8 bf1 = *(const half8*)(bn1base + 128);
  #pragma unroll
  for (int ks = 0; ks < 8; ++ks) {
    half8 nb0, nb1;
    if (ks < 7) {
      nb0 = *(const half8*)(bn1base + (ks + 1) * 4096);
      nb1 = *(const half8*)(bn1base + (ks + 1) * 4096 + 128);
    }
    #pragma unroll
    for (int mt = 0; mt < 4; ++mt) {
      half8 a = *(const half8*)&Y[(mt * 16 + c) * YS + ks * 32 + q * 8];
      acc[mt][0] = __builtin_amdgcn_mfma_f32_16x16x32_f16(a, bf0, acc[mt][0], 0, 0, 0);
      acc[mt][1] = __builtin_amdgcn_mfma_f32_16x16x32_f16(a, bf1, acc[mt][1], 0, 0, 0);
    }
    bf0 = nb0; bf1 = nb1;
  }
  const f16* bn2base = BN2 + ((size_t)(q * 128 + colBase + c)) * 8;
  half8 d0 = *(const half8*)(bn2base);
  half8 d1 = *(const half8*)(bn2base + 128);
  __syncthreads();
  f16* T = Y;
  #pragma unroll
  for (int mt = 0; mt < 4; ++mt)
    #pragma unroll
    for (int nt = 0; nt < 2; ++nt)
      #pragma unroll
      for (int r = 0; r < 4; ++r) {
        float v = acc[mt][nt][r];
        T[(mt * 16 + q * 4 + r) * TS + colBase + nt * 16 + c] = (f16)(v > 0.f ? v : 0.f);
      }
  __syncthreads();
  f32x4 m2[4][2];
  {
    float b0 = bn2[colBase + c], b1 = bn2[colBase + 16 + c];
    #pragma unroll
    for (int mt = 0; mt < 4; ++mt) {
      m2[mt][0] = (f32x4){b0, b0, b0, b0};
      m2[mt][1] = (f32x4){b1, b1, b1, b1};
    }
  }
  #pragma unroll
  for (int kk = 0; kk < 4; ++kk) {
    half8 n0, n1;
    if (kk < 3) {
      n0 = *(const half8*)(bn2base + (kk + 1) * 4096);
      n1 = *(const half8*)(bn2base + (kk + 1) * 4096 + 128);
    }
    #pragma unroll
    for (int mt = 0; mt < 4; ++mt) {
      half8 a = *(const half8*)&T[(mt * 16 + c) * TS + kk * 32 + q * 8];
      m2[mt][0] = __builtin_amdgcn_mfma_f32_16x16x32_f16(a, d0, m2[mt][0], 0, 0, 0);
      m2[mt][1] = __builtin_amdgcn_mfma_f32_16x16x32_f16(a, d1, m2[mt][1], 0, 0, 0);
    }
    d0 = n0; d1 = n1;
  }
  #pragma unroll
  for (int mt = 0; mt < 4; ++mt)
    #pragma unroll
    for (int r = 0; r < 4; ++r) {
      int g = n0 + mt * 16 + q * 4 + r;
      if (g < N_NODES) {
        float* o = out + (size_t)g * HID + colBase + c;
        o[0]  = m2[mt][0][r];
        o[16] = m2[mt][1][r];
      }
    }
}

extern "C" void kernel_launch(void* const* d_in, const int* in_sizes, int n_in,
                              void* d_out, int out_size, void* d_ws, size_t ws_size,
                              hipStream_t stream) {
  const float* h    = (const float*)d_in[0];
  const int*   eidx = (const int*)d_in[1];
  const float* eattr= (const float*)d_in[2];
  const float* We1  = (const float*)d_in[3];
  const float* be1  = (const float*)d_in[4];
  const float* We2  = (const float*)d_in[5];
  const float* be2  = (const float*)d_in[6];
  const float* Wg   = (const float*)d_in[7];
  const float* bg   = (const float*)d_in[8];
  const float* Wn1  = (const float*)d_in[9];
  const float* bn1  = (const float*)d_in[10];
  const float* Wn2  = (const float*)d_in[11];
  const float* bn2  = (const float*)d_in[12];
  float* out = (float*)d_out;
  char* ws = (char*)d_ws;

  if (ws_size >= CSR_TOTAL) {
    f16* medge = (f16*)(ws + OFF_MEDGE);
    f16* h16   = (f16*)(ws + OFF_H16C);
    f16* Wp    = (f16*)(ws + OFF_WC);
    int* cnt   = (int*)(ws + OFF_CNT);
    int* offs  = (int*)(ws + OFF_OFFS);
    int* cur   = (int*)(ws + OFF_CUR);
    int* bsum  = (int*)(ws + OFF_BSUM);
    int* elist = (int*)(ws + OFF_ELIST);

    hipMemsetAsync(cnt, 0, 50176 * sizeof(int), stream);
    pack_weights<<<400, 256, 0, stream>>>(We1, We2, Wn1, Wn2, Wp);
    convert_h<<<3125, 256, 0, stream>>>(h, h16);
    hist_kernel<<<3125, 256, 0, stream>>>(eidx, cnt);
    scan1_kernel<<<49, 256, 0, stream>>>(cnt, offs, bsum);
    scan2_kernel<<<196, 256, 0, stream>>>(offs, cur, bsum);
    scatter_kernel<<<3125, 256, 0, stream>>>(eidx, cur, elist);
    edge_kernel<<<N_EDGES / 64, 256, 0, stream>>>(h16, eidx, eattr, Wp, be1, be2, Wg, bg,
                                                  nullptr, medge);
    node_kernel_csr<<<(N_NODES + 63) / 64, 256, 0, stream>>>(medge, elist, offs, cnt, h16,
                                                             Wp, bn1, bn2, out);
  } else {
    float* mi  = (float*)(ws + OFF_MI);
    f16*   h16 = (f16*)(ws + OFF_H16);
    f16*   Wp  = (f16*)(ws + OFF_W);

    hipMemsetAsync(mi, 0, (size_t)N_NODES * HID * sizeof(float), stream);
    pack_weights<<<400, 256, 0, stream>>>(We1, We2, Wn1, Wn2, Wp);
    convert_h<<<3125, 256, 0, stream>>>(h, h16);
    edge_kernel<<<N_EDGES / 64, 256, 0, stream>>>(h16, eidx, eattr, Wp, be1, be2, Wg, bg,
                                                  mi, nullptr);
    node_kernel<<<(N_NODES + 63) / 64, 256, 0, stream>>>(mi, h16, Wp, bn1, bn2, out);
  }
}